// Round 1
// baseline (1370.042 us; speedup 1.0000x reference)
//
#include <hip/hip_runtime.h>
#include <hip/hip_bf16.h>
#include <float.h>
#include <math.h>

// Problem constants (from reference): B=2, L=2048, D=1024, NH=16, HD=64
#define BB  2
#define LLEN 2048
#define DD  1024
#define NHH 16
#define HDD 64
#define MROWS (BB * LLEN)   // 4096

// ---------------------------------------------------------------------------
// GEMM: Y = X[M,K] @ W[K,N] + bias[N]; M=4096, N=K=1024.
// MODE 0: plain store Y[m*N+n]  (final output projection)
// MODE 1: store transposed into [B, NH, L, HD] layout (QKV projections)
// 64x64 tile, 256 threads, each thread 4x4 micro-tile, K-tile=16.
// ---------------------------------------------------------------------------
template <int MODE>
__global__ __launch_bounds__(256) void gemm_k(const float* __restrict__ X,
                                              const float* __restrict__ W,
                                              const float* __restrict__ bias,
                                              float* __restrict__ Y) {
    const int N = DD, K = DD;
    __shared__ float As[16][68];  // [k][m], row stride 68 floats = 272B (16B aligned)
    __shared__ float Bs[16][68];  // [k][n]

    const int tid = threadIdx.x;
    const int bm = blockIdx.y * 64;
    const int bn = blockIdx.x * 64;
    const int tm = tid >> 4;      // 0..15
    const int tn = tid & 15;      // 0..15

    // loader mapping
    const int ar  = tid >> 2;         // 0..63 (A row within tile)
    const int ac4 = (tid & 3) * 4;    // 0,4,8,12 (A k-offset)
    const int br  = tid >> 4;         // 0..15 (B k-row)
    const int bc4 = (tid & 15) * 4;   // 0..60 (B col offset)

    float acc[4][4];
#pragma unroll
    for (int i = 0; i < 4; ++i)
#pragma unroll
        for (int j = 0; j < 4; ++j) acc[i][j] = 0.f;

    for (int k0 = 0; k0 < K; k0 += 16) {
        __syncthreads();
        // A tile 64x16 -> As[k][m] (transposed)
        float4 av = *reinterpret_cast<const float4*>(&X[(size_t)(bm + ar) * K + k0 + ac4]);
        As[ac4 + 0][ar] = av.x;
        As[ac4 + 1][ar] = av.y;
        As[ac4 + 2][ar] = av.z;
        As[ac4 + 3][ar] = av.w;
        // B tile 16x64 -> Bs[k][n]
        float4 bv = *reinterpret_cast<const float4*>(&W[(size_t)(k0 + br) * N + bn + bc4]);
        Bs[br][bc4 + 0] = bv.x;
        Bs[br][bc4 + 1] = bv.y;
        Bs[br][bc4 + 2] = bv.z;
        Bs[br][bc4 + 3] = bv.w;
        __syncthreads();

#pragma unroll
        for (int kk = 0; kk < 16; ++kk) {
            float4 a = *reinterpret_cast<const float4*>(&As[kk][tm * 4]);
            float4 b = *reinterpret_cast<const float4*>(&Bs[kk][tn * 4]);
            float aa[4] = {a.x, a.y, a.z, a.w};
            float bb[4] = {b.x, b.y, b.z, b.w};
#pragma unroll
            for (int i = 0; i < 4; ++i)
#pragma unroll
                for (int j = 0; j < 4; ++j) acc[i][j] += aa[i] * bb[j];
        }
    }

#pragma unroll
    for (int i = 0; i < 4; ++i) {
        int m = bm + tm * 4 + i;
#pragma unroll
        for (int j = 0; j < 4; ++j) {
            int n = bn + tn * 4 + j;
            float val = acc[i][j] + bias[n];
            if (MODE == 0) {
                Y[(size_t)m * N + n] = val;
            } else {
                int b = m >> 11;        // m / L
                int l = m & (LLEN - 1); // m % L
                int h = n >> 6;         // n / HD
                int hd = n & (HDD - 1); // n % HD
                Y[(((size_t)(b * NHH + h)) * LLEN + l) * HDD + hd] = val;
            }
        }
    }
}

// ---------------------------------------------------------------------------
// RoPE in-place on [B*NH, L, HD]; pairs (d, d+32), angle = l * base^(-d/32)
// ---------------------------------------------------------------------------
__global__ __launch_bounds__(256) void rope_k(float* __restrict__ T) {
    int idx = blockIdx.x * blockDim.x + threadIdx.x;  // B*NH*L*32 threads
    int d = idx & 31;
    int l = (idx >> 5) & (LLEN - 1);
    int bh = idx >> 16;  // < 32
    // ln(10000)/32
    float ang = (float)l * __expf(-(float)d * 0.28782313662425572f);
    float s, c;
    __sincosf(ang, &s, &c);
    float* base = T + ((size_t)bh * LLEN + l) * HDD;
    float x1 = base[d];
    float x2 = base[d + 32];
    base[d]      = x1 * c - x2 * s;
    base[d + 32] = x2 * c + x1 * s;
}

// ---------------------------------------------------------------------------
// Flash-style causal attention.
// Grid: (L/64 q-tiles, B*NH). Block 256 threads.
// Per block: 64 q-rows; iterate kv tiles of 32 rows with online softmax.
// Thread mapping: r = tid>>2 (q-row), cg = tid&3.
//   S phase:  thread computes S[r][cg*8 + 0..7]
//   PV phase: thread accumulates O[r][cg*16 + 0..15]
// Writes ctx in [B, L, D] layout (untransposed) for the output GEMM.
// ---------------------------------------------------------------------------
__global__ __launch_bounds__(256) void attn_k(const float* __restrict__ Qt,
                                              const float* __restrict__ Kt,
                                              const float* __restrict__ Vt,
                                              float* __restrict__ ctx) {
    __shared__ float Qs[64][68];
    __shared__ float Ks[32][68];
    __shared__ float Vs[32][68];
    __shared__ float Ss[64][36];

    const int tid = threadIdx.x;
    const int q0 = blockIdx.x * 64;
    const int bh = blockIdx.y;

    const float* Qb = Qt + (size_t)bh * LLEN * HDD;
    const float* Kb = Kt + (size_t)bh * LLEN * HDD;
    const float* Vb = Vt + (size_t)bh * LLEN * HDD;

    // load Q tile (64x64) via float4
    for (int i = tid; i < 64 * 16; i += 256) {
        int r = i >> 4;
        int d4 = (i & 15) * 4;
        float4 v = *reinterpret_cast<const float4*>(&Qb[(size_t)(q0 + r) * HDD + d4]);
        Qs[r][d4 + 0] = v.x;
        Qs[r][d4 + 1] = v.y;
        Qs[r][d4 + 2] = v.z;
        Qs[r][d4 + 3] = v.w;
    }

    const int r = tid >> 2;
    const int cg = tid & 3;
    const int gq = q0 + r;

    float m = -FLT_MAX, lsum = 0.f;
    float O[16];
#pragma unroll
    for (int i = 0; i < 16; ++i) O[i] = 0.f;

    const int nkt = (q0 >> 5) + 2;  // kv tiles covering k <= q0+63
    for (int t = 0; t < nkt; ++t) {
        const int k0 = t * 32;
        __syncthreads();  // previous PV reads done before overwriting K/V
        for (int i = tid; i < 32 * 16; i += 256) {
            int kr = i >> 4;
            int d4 = (i & 15) * 4;
            float4 kv = *reinterpret_cast<const float4*>(&Kb[(size_t)(k0 + kr) * HDD + d4]);
            float4 vv = *reinterpret_cast<const float4*>(&Vb[(size_t)(k0 + kr) * HDD + d4]);
            Ks[kr][d4 + 0] = kv.x; Ks[kr][d4 + 1] = kv.y;
            Ks[kr][d4 + 2] = kv.z; Ks[kr][d4 + 3] = kv.w;
            Vs[kr][d4 + 0] = vv.x; Vs[kr][d4 + 1] = vv.y;
            Vs[kr][d4 + 2] = vv.z; Vs[kr][d4 + 3] = vv.w;
        }
        __syncthreads();

        // S = Q K^T for this thread's 8 columns
        float acc[8];
#pragma unroll
        for (int j = 0; j < 8; ++j) acc[j] = 0.f;
        for (int d = 0; d < 64; d += 4) {
            float4 qv = *reinterpret_cast<const float4*>(&Qs[r][d]);
#pragma unroll
            for (int j = 0; j < 8; ++j) {
                float4 kv = *reinterpret_cast<const float4*>(&Ks[cg * 8 + j][d]);
                acc[j] += qv.x * kv.x + qv.y * kv.y + qv.z * kv.z + qv.w * kv.w;
            }
        }

        // scale + causal mask + online softmax
        float pmax = -FLT_MAX;
#pragma unroll
        for (int j = 0; j < 8; ++j) {
            int gk = k0 + cg * 8 + j;
            acc[j] = (gk <= gq) ? acc[j] * 0.125f : -FLT_MAX;
            pmax = fmaxf(pmax, acc[j]);
        }
        pmax = fmaxf(pmax, __shfl_xor(pmax, 1));
        pmax = fmaxf(pmax, __shfl_xor(pmax, 2));
        float mnew = fmaxf(m, pmax);
        float corr = __expf(m - mnew);
        float ps = 0.f;
#pragma unroll
        for (int j = 0; j < 8; ++j) {
            float p = __expf(acc[j] - mnew);
            Ss[r][cg * 8 + j] = p;
            ps += p;
        }
        ps += __shfl_xor(ps, 1);
        ps += __shfl_xor(ps, 2);
        lsum = lsum * corr + ps;
        m = mnew;
#pragma unroll
        for (int i = 0; i < 16; ++i) O[i] *= corr;
        __syncthreads();  // Ss visible to all row threads

        // O += P @ V for this thread's 16 output cols
        for (int k = 0; k < 32; ++k) {
            float pv = Ss[r][k];
            float4 v0 = *reinterpret_cast<const float4*>(&Vs[k][cg * 16 + 0]);
            float4 v1 = *reinterpret_cast<const float4*>(&Vs[k][cg * 16 + 4]);
            float4 v2 = *reinterpret_cast<const float4*>(&Vs[k][cg * 16 + 8]);
            float4 v3 = *reinterpret_cast<const float4*>(&Vs[k][cg * 16 + 12]);
            O[0]  += pv * v0.x; O[1]  += pv * v0.y; O[2]  += pv * v0.z; O[3]  += pv * v0.w;
            O[4]  += pv * v1.x; O[5]  += pv * v1.y; O[6]  += pv * v1.z; O[7]  += pv * v1.w;
            O[8]  += pv * v2.x; O[9]  += pv * v2.y; O[10] += pv * v2.z; O[11] += pv * v2.w;
            O[12] += pv * v3.x; O[13] += pv * v3.y; O[14] += pv * v3.z; O[15] += pv * v3.w;
        }
    }

    float invl = 1.0f / lsum;
    int b = bh >> 4;
    int h = bh & 15;
    float* dst = ctx + ((size_t)(b * LLEN + gq)) * DD + h * HDD + cg * 16;
#pragma unroll
    for (int i = 0; i < 16; ++i) dst[i] = O[i] * invl;
}

// ---------------------------------------------------------------------------
extern "C" void kernel_launch(void* const* d_in, const int* in_sizes, int n_in,
                              void* d_out, int out_size, void* d_ws, size_t ws_size,
                              hipStream_t stream) {
    const float* x    = (const float*)d_in[0];
    const float* wq_w = (const float*)d_in[1];
    const float* wq_b = (const float*)d_in[2];
    const float* wk_w = (const float*)d_in[3];
    const float* wk_b = (const float*)d_in[4];
    const float* wv_w = (const float*)d_in[5];
    const float* wv_b = (const float*)d_in[6];
    const float* wo_w = (const float*)d_in[7];
    const float* wo_b = (const float*)d_in[8];
    float* out = (float*)d_out;

    const size_t TEN = (size_t)BB * NHH * LLEN * HDD;  // 4,194,304 floats
    float* qT  = (float*)d_ws;
    float* kT  = qT + TEN;
    float* vT  = kT + TEN;
    float* ctx = vT + TEN;

    dim3 gblock(256);
    dim3 ggrid(DD / 64, MROWS / 64);  // (16, 64)

    hipLaunchKernelGGL((gemm_k<1>), ggrid, gblock, 0, stream, x, wq_w, wq_b, qT);
    hipLaunchKernelGGL((gemm_k<1>), ggrid, gblock, 0, stream, x, wk_w, wk_b, kT);
    hipLaunchKernelGGL((gemm_k<1>), ggrid, gblock, 0, stream, x, wv_w, wv_b, vT);

    int rope_threads = BB * NHH * LLEN * 32;  // 2,097,152
    hipLaunchKernelGGL(rope_k, dim3(rope_threads / 256), dim3(256), 0, stream, qT);
    hipLaunchKernelGGL(rope_k, dim3(rope_threads / 256), dim3(256), 0, stream, kT);

    hipLaunchKernelGGL(attn_k, dim3(LLEN / 64, BB * NHH), dim3(256), 0, stream,
                       qT, kT, vT, ctx);

    hipLaunchKernelGGL((gemm_k<0>), ggrid, gblock, 0, stream, ctx, wo_w, wo_b, out);
}

// Round 2
// 745.847 us; speedup vs baseline: 1.8369x; 1.8369x over previous
//
#include <hip/hip_runtime.h>
#include <hip/hip_bf16.h>
#include <float.h>
#include <math.h>

// Problem constants: B=2, L=2048, D=1024, NH=16, HD=64
#define BB  2
#define LLEN 2048
#define DD  1024
#define NHH 16
#define HDD 64
#define MROWS (BB * LLEN)   // 4096

typedef __bf16 bf16x8 __attribute__((ext_vector_type(8)));
typedef float  f32x4  __attribute__((ext_vector_type(4)));

// ---------------------------------------------------------------------------
// fp32 GEMM: Y = X[M,K] @ W[K,N] + bias[N]; M=4096, N=K=1024.
// MODE 0: plain store Y[m*N+n]; MODE 1: store into [B, NH, L, HD]
// ---------------------------------------------------------------------------
template <int MODE>
__global__ __launch_bounds__(256) void gemm_k(const float* __restrict__ X,
                                              const float* __restrict__ W,
                                              const float* __restrict__ bias,
                                              float* __restrict__ Y) {
    const int N = DD, K = DD;
    __shared__ float As[16][68];
    __shared__ float Bs[16][68];

    const int tid = threadIdx.x;
    const int bm = blockIdx.y * 64;
    const int bn = blockIdx.x * 64;
    const int tm = tid >> 4;
    const int tn = tid & 15;

    const int ar  = tid >> 2;
    const int ac4 = (tid & 3) * 4;
    const int br  = tid >> 4;
    const int bc4 = (tid & 15) * 4;

    float acc[4][4];
#pragma unroll
    for (int i = 0; i < 4; ++i)
#pragma unroll
        for (int j = 0; j < 4; ++j) acc[i][j] = 0.f;

    for (int k0 = 0; k0 < K; k0 += 16) {
        __syncthreads();
        float4 av = *reinterpret_cast<const float4*>(&X[(size_t)(bm + ar) * K + k0 + ac4]);
        As[ac4 + 0][ar] = av.x;
        As[ac4 + 1][ar] = av.y;
        As[ac4 + 2][ar] = av.z;
        As[ac4 + 3][ar] = av.w;
        float4 bv = *reinterpret_cast<const float4*>(&W[(size_t)(k0 + br) * N + bn + bc4]);
        Bs[br][bc4 + 0] = bv.x;
        Bs[br][bc4 + 1] = bv.y;
        Bs[br][bc4 + 2] = bv.z;
        Bs[br][bc4 + 3] = bv.w;
        __syncthreads();

#pragma unroll
        for (int kk = 0; kk < 16; ++kk) {
            float4 a = *reinterpret_cast<const float4*>(&As[kk][tm * 4]);
            float4 b = *reinterpret_cast<const float4*>(&Bs[kk][tn * 4]);
            float aa[4] = {a.x, a.y, a.z, a.w};
            float bb[4] = {b.x, b.y, b.z, b.w};
#pragma unroll
            for (int i = 0; i < 4; ++i)
#pragma unroll
                for (int j = 0; j < 4; ++j) acc[i][j] += aa[i] * bb[j];
        }
    }

#pragma unroll
    for (int i = 0; i < 4; ++i) {
        int m = bm + tm * 4 + i;
#pragma unroll
        for (int j = 0; j < 4; ++j) {
            int n = bn + tn * 4 + j;
            float val = acc[i][j] + bias[n];
            if (MODE == 0) {
                Y[(size_t)m * N + n] = val;
            } else {
                int b = m >> 11;
                int l = m & (LLEN - 1);
                int h = n >> 6;
                int hd = n & (HDD - 1);
                Y[(((size_t)(b * NHH + h)) * LLEN + l) * HDD + hd] = val;
            }
        }
    }
}

// ---------------------------------------------------------------------------
// RoPE + convert to bf16: in fp32 [BH][L][HD] -> out bf16 [BH][L][HD]
// pairs (d, d+32), angle = l * base^(-d/32)
// ---------------------------------------------------------------------------
__global__ __launch_bounds__(256) void rope_cvt_k(const float* __restrict__ in,
                                                  __hip_bfloat16* __restrict__ out) {
    int idx = blockIdx.x * blockDim.x + threadIdx.x;  // BH*L*32 threads
    int d = idx & 31;
    int l = (idx >> 5) & (LLEN - 1);
    int bh = idx >> 16;
    float ang = (float)l * __expf(-(float)d * 0.28782313662425572f);  // ln(1e4)/32
    float s, c;
    __sincosf(ang, &s, &c);
    const float* base = in + ((size_t)bh * LLEN + l) * HDD;
    float x1 = base[d];
    float x2 = base[d + 32];
    __hip_bfloat16* ob = out + ((size_t)bh * LLEN + l) * HDD;
    ob[d]      = __float2bfloat16(x1 * c - x2 * s);
    ob[d + 32] = __float2bfloat16(x2 * c + x1 * s);
}

// ---------------------------------------------------------------------------
// V convert + transpose: fp32 [BH][L][HD] -> bf16 [BH][HD][L]
// ---------------------------------------------------------------------------
__global__ __launch_bounds__(256) void vcvt_k(const float* __restrict__ in,
                                              __hip_bfloat16* __restrict__ out) {
    __shared__ float T[64][68];
    const int bh = blockIdx.y;
    const int l0 = blockIdx.x * 64;
    const int tid = threadIdx.x;
    for (int i = tid; i < 64 * 16; i += 256) {
        int r = i >> 4, c4 = (i & 15) * 4;
        float4 v = *reinterpret_cast<const float4*>(&in[((size_t)bh * LLEN + l0 + r) * HDD + c4]);
        T[r][c4] = v.x; T[r][c4 + 1] = v.y; T[r][c4 + 2] = v.z; T[r][c4 + 3] = v.w;
    }
    __syncthreads();
    int d  = tid >> 2;           // 0..63
    int lc = (tid & 3) * 16;     // 0,16,32,48
    __hip_bfloat16* ob = out + ((size_t)bh * HDD + d) * LLEN + l0 + lc;
#pragma unroll
    for (int j = 0; j < 16; ++j) ob[j] = __float2bfloat16(T[lc + j][d]);
}

// ---------------------------------------------------------------------------
// MFMA flash attention (causal). Grid (L/64, B*NH), 256 thr = 4 waves.
// Wave w owns q-rows [q0 + w*16, +16). KV tiles of 32. No block barriers
// (waves fully independent; per-wave LDS P buffer, XOR-swizzled).
//
// mfma_f32_16x16x32_bf16 layouts (verified m89/m93):
//  A: lane l holds A[l%16][(l/16)*8 + j], j=0..7 (8 consecutive k)
//  B: lane l holds B[(l/16)*8 + j][l%16]  (== 8 consecutive k of B^T row l%16)
//  D: lane l reg i -> D[(l>>4)*4 + i][l&15]
// ---------------------------------------------------------------------------
__global__ __launch_bounds__(256) void attn_mfma_k(const __bf16* __restrict__ Q,
                                                   const __bf16* __restrict__ K,
                                                   const __bf16* __restrict__ Vt,
                                                   float* __restrict__ ctx) {
    __shared__ float P_lds[4][16][32];

    const int tid  = threadIdx.x;
    const int w    = tid >> 6;
    const int lane = tid & 63;
    const int lr   = lane & 15;   // row-in-16 (A) / col-in-16 (B,D)
    const int lg   = lane >> 4;   // k-group / row-group
    const int bh   = blockIdx.y;
    const int qbase = blockIdx.x * 64 + w * 16;

    const __bf16* Qh = Q  + (size_t)bh * LLEN * HDD;
    const __bf16* Kh = K  + (size_t)bh * LLEN * HDD;
    const __bf16* Vh = Vt + (size_t)bh * HDD * LLEN;

    // Q A-fragments for d=0..31 (s=0) and d=32..63 (s=1)
    bf16x8 qa0 = *reinterpret_cast<const bf16x8*>(Qh + (size_t)(qbase + lr) * HDD + lg * 8);
    bf16x8 qa1 = *reinterpret_cast<const bf16x8*>(Qh + (size_t)(qbase + lr) * HDD + 32 + lg * 8);

    f32x4 o0 = {0.f, 0.f, 0.f, 0.f}, o1 = o0, o2 = o0, o3 = o0;
    float mrow[4] = {-FLT_MAX, -FLT_MAX, -FLT_MAX, -FLT_MAX};
    float lrow[4] = {0.f, 0.f, 0.f, 0.f};

    const int nk = (qbase + 47) >> 5;  // kv tiles of 32 covering k <= qbase+15
    for (int t = 0; t < nk; ++t) {
        const int k0 = t * 32;

        // K B-fragments: col tiles c=0,1; k-steps s=0,1
        const __bf16* Kb = Kh + (size_t)(k0 + lr) * HDD + lg * 8;
        bf16x8 kb00 = *reinterpret_cast<const bf16x8*>(Kb);
        bf16x8 kb01 = *reinterpret_cast<const bf16x8*>(Kb + 32);
        bf16x8 kb10 = *reinterpret_cast<const bf16x8*>(Kb + 16 * HDD);
        bf16x8 kb11 = *reinterpret_cast<const bf16x8*>(Kb + 16 * HDD + 32);

        f32x4 s0 = {0.f, 0.f, 0.f, 0.f}, s1 = s0;
        s0 = __builtin_amdgcn_mfma_f32_16x16x32_bf16(qa0, kb00, s0, 0, 0, 0);
        s0 = __builtin_amdgcn_mfma_f32_16x16x32_bf16(qa1, kb01, s0, 0, 0, 0);
        s1 = __builtin_amdgcn_mfma_f32_16x16x32_bf16(qa0, kb10, s1, 0, 0, 0);
        s1 = __builtin_amdgcn_mfma_f32_16x16x32_bf16(qa1, kb11, s1, 0, 0, 0);

        // V B-fragments (V^T rows are contiguous): d-tiles 0..3
        const __bf16* Vb = Vh + (size_t)lr * LLEN + k0 + lg * 8;
        bf16x8 vb0 = *reinterpret_cast<const bf16x8*>(Vb);
        bf16x8 vb1 = *reinterpret_cast<const bf16x8*>(Vb + 16 * LLEN);
        bf16x8 vb2 = *reinterpret_cast<const bf16x8*>(Vb + 32 * LLEN);
        bf16x8 vb3 = *reinterpret_cast<const bf16x8*>(Vb + 48 * LLEN);

        // online softmax (fp32), rows qbase+lg*4+i, cols k0+lr / k0+16+lr
        float p0[4], p1[4];
#pragma unroll
        for (int i = 0; i < 4; ++i) {
            int row = qbase + lg * 4 + i;
            float a = s0[i] * 0.125f;
            float b = s1[i] * 0.125f;
            if (k0 + lr > row)      a = -FLT_MAX;
            if (k0 + 16 + lr > row) b = -FLT_MAX;
            float rm = fmaxf(a, b);
            rm = fmaxf(rm, __shfl_xor(rm, 1));
            rm = fmaxf(rm, __shfl_xor(rm, 2));
            rm = fmaxf(rm, __shfl_xor(rm, 4));
            rm = fmaxf(rm, __shfl_xor(rm, 8));
            float mn   = fmaxf(mrow[i], rm);
            float corr = __expf(mrow[i] - mn);
            float pa = __expf(a - mn);
            float pb = __expf(b - mn);
            float rs = pa + pb;
            rs += __shfl_xor(rs, 1);
            rs += __shfl_xor(rs, 2);
            rs += __shfl_xor(rs, 4);
            rs += __shfl_xor(rs, 8);
            lrow[i] = lrow[i] * corr + rs;
            mrow[i] = mn;
            o0[i] *= corr; o1[i] *= corr; o2[i] *= corr; o3[i] *= corr;
            p0[i] = pa; p1[i] = pb;
        }

        // P (D-layout) -> LDS, XOR-swizzled on 4-word groups: phys_g4 = g4 ^ (row&7)
#pragma unroll
        for (int i = 0; i < 4; ++i) {
            int row = lg * 4 + i;
            int h7  = row & 7;
            P_lds[w][row][((((lr) >> 2) ^ h7) << 2) | (lr & 3)]      = p0[i];
            P_lds[w][row][((((16 + lr) >> 2) ^ h7) << 2) | (lr & 3)] = p1[i];
        }

        // read back as A-fragment: row lr, logical cols lg*8 .. lg*8+7
        const f32x4* pr0 = reinterpret_cast<const f32x4*>(&P_lds[w][lr][((2 * lg) ^ (lr & 7)) << 2]);
        const f32x4* pr1 = reinterpret_cast<const f32x4*>(&P_lds[w][lr][((2 * lg + 1) ^ (lr & 7)) << 2]);
        f32x4 f0 = *pr0, f1 = *pr1;
        bf16x8 pfrag;
        pfrag[0] = (__bf16)f0[0]; pfrag[1] = (__bf16)f0[1];
        pfrag[2] = (__bf16)f0[2]; pfrag[3] = (__bf16)f0[3];
        pfrag[4] = (__bf16)f1[0]; pfrag[5] = (__bf16)f1[1];
        pfrag[6] = (__bf16)f1[2]; pfrag[7] = (__bf16)f1[3];

        o0 = __builtin_amdgcn_mfma_f32_16x16x32_bf16(pfrag, vb0, o0, 0, 0, 0);
        o1 = __builtin_amdgcn_mfma_f32_16x16x32_bf16(pfrag, vb1, o1, 0, 0, 0);
        o2 = __builtin_amdgcn_mfma_f32_16x16x32_bf16(pfrag, vb2, o2, 0, 0, 0);
        o3 = __builtin_amdgcn_mfma_f32_16x16x32_bf16(pfrag, vb3, o3, 0, 0, 0);
    }

    // epilogue: divide by row sum, write ctx [B, L, D]
    const int b = bh >> 4, h = bh & 15;
#pragma unroll
    for (int i = 0; i < 4; ++i) {
        float inv = 1.0f / lrow[i];
        float* dst = ctx + ((size_t)(b * LLEN + qbase + lg * 4 + i)) * DD + h * HDD + lr;
        dst[0]  = o0[i] * inv;
        dst[16] = o1[i] * inv;
        dst[32] = o2[i] * inv;
        dst[48] = o3[i] * inv;
    }
}

// ---------------------------------------------------------------------------
extern "C" void kernel_launch(void* const* d_in, const int* in_sizes, int n_in,
                              void* d_out, int out_size, void* d_ws, size_t ws_size,
                              hipStream_t stream) {
    const float* x    = (const float*)d_in[0];
    const float* wq_w = (const float*)d_in[1];
    const float* wq_b = (const float*)d_in[2];
    const float* wk_w = (const float*)d_in[3];
    const float* wk_b = (const float*)d_in[4];
    const float* wv_w = (const float*)d_in[5];
    const float* wv_b = (const float*)d_in[6];
    const float* wo_w = (const float*)d_in[7];
    const float* wo_b = (const float*)d_in[8];
    float* out = (float*)d_out;

    const size_t TEN = (size_t)BB * NHH * LLEN * HDD;  // 4,194,304 floats
    float* qT = (float*)d_ws;          // fp32 Q [BH][L][HD]; later reused as ctx
    float* kT = qT + TEN;              // fp32 K
    float* vT = kT + TEN;              // fp32 V; later reused as k16 (bf16)
    __hip_bfloat16* k16 = (__hip_bfloat16*)vT;
    __hip_bfloat16* q16 = (__hip_bfloat16*)(vT + TEN);
    __hip_bfloat16* v16 = (__hip_bfloat16*)(vT + TEN + TEN / 2);
    float* ctx = qT;
    // total ws: 16 M floats = 64 MB

    dim3 gblock(256);
    dim3 ggrid(DD / 64, MROWS / 64);  // (16, 64)

    hipLaunchKernelGGL((gemm_k<1>), ggrid, gblock, 0, stream, x, wq_w, wq_b, qT);
    hipLaunchKernelGGL((gemm_k<1>), ggrid, gblock, 0, stream, x, wk_w, wk_b, kT);
    hipLaunchKernelGGL((gemm_k<1>), ggrid, gblock, 0, stream, x, wv_w, wv_b, vT);

    // V -> bf16 transposed [BH][HD][L] (must run before k16 overwrites vT)
    hipLaunchKernelGGL(vcvt_k, dim3(LLEN / 64, BB * NHH), gblock, 0, stream, vT, v16);

    int rope_threads = BB * NHH * LLEN * 32;  // 2,097,152
    hipLaunchKernelGGL(rope_cvt_k, dim3(rope_threads / 256), gblock, 0, stream, qT, q16);
    hipLaunchKernelGGL(rope_cvt_k, dim3(rope_threads / 256), gblock, 0, stream, kT, k16);

    hipLaunchKernelGGL(attn_mfma_k, dim3(LLEN / 64, BB * NHH), gblock, 0, stream,
                       (const __bf16*)q16, (const __bf16*)k16, (const __bf16*)v16, ctx);

    hipLaunchKernelGGL((gemm_k<0>), ggrid, gblock, 0, stream, ctx, wo_w, wo_b, out);
}

// Round 3
// 321.014 us; speedup vs baseline: 4.2679x; 2.3234x over previous
//
#include <hip/hip_runtime.h>
#include <hip/hip_bf16.h>
#include <float.h>
#include <math.h>

// Problem constants: B=2, L=2048, D=1024, NH=16, HD=64
#define BB  2
#define LLEN 2048
#define DD  1024
#define NHH 16
#define HDD 64
#define MROWS (BB * LLEN)   // 4096

typedef __bf16 bf16x8 __attribute__((ext_vector_type(8)));
typedef float  f32x4  __attribute__((ext_vector_type(4)));

static __device__ __forceinline__ ushort f2bf(float f) {
    __hip_bfloat16 h = __float2bfloat16(f);
    return *reinterpret_cast<ushort*>(&h);
}

__device__ __forceinline__ void gload16(const void* g, void* l) {
    __builtin_amdgcn_global_load_lds(
        (const __attribute__((address_space(1))) void*)g,
        (__attribute__((address_space(3))) void*)l, 16, 0, 0);
}

// ---------------------------------------------------------------------------
// x fp32 -> bf16, 4 elems/thread
// ---------------------------------------------------------------------------
__global__ __launch_bounds__(256) void cvt_x_k(const float* __restrict__ in,
                                               ushort* __restrict__ out) {
    int idx = blockIdx.x * 256 + threadIdx.x;
    float4 v = reinterpret_cast<const float4*>(in)[idx];
    ushort4 o;
    o.x = f2bf(v.x); o.y = f2bf(v.y); o.z = f2bf(v.z); o.w = f2bf(v.w);
    reinterpret_cast<ushort4*>(out)[idx] = o;
}

// ---------------------------------------------------------------------------
// Weight transpose+convert: in fp32 [1024][1024] -> out bf16 [N][K] (out[n][k]=in[k][n])
// ---------------------------------------------------------------------------
__global__ __launch_bounds__(256) void wt_cvt_k(const float* __restrict__ in,
                                                ushort* __restrict__ out) {
    __shared__ float T[64][65];
    const int r0 = blockIdx.y * 64, c0 = blockIdx.x * 64;
    const int tid = threadIdx.x;
    for (int i = tid; i < 64 * 16; i += 256) {
        int r = i >> 4, c4 = (i & 15) * 4;
        float4 v = *reinterpret_cast<const float4*>(&in[(size_t)(r0 + r) * DD + c0 + c4]);
        T[r][c4 + 0] = v.x; T[r][c4 + 1] = v.y; T[r][c4 + 2] = v.z; T[r][c4 + 3] = v.w;
    }
    __syncthreads();
    for (int i = tid; i < 64 * 16; i += 256) {
        int rr = i >> 4, cc4 = (i & 15) * 4;
        ushort4 o;
        o.x = f2bf(T[cc4 + 0][rr]);
        o.y = f2bf(T[cc4 + 1][rr]);
        o.z = f2bf(T[cc4 + 2][rr]);
        o.w = f2bf(T[cc4 + 3][rr]);
        *reinterpret_cast<ushort4*>(&out[(size_t)(c0 + rr) * DD + r0 + cc4]) = o;
    }
}

// ---------------------------------------------------------------------------
// bf16 MFMA GEMM: C = A[M,K] @ Bt[N,K]^T + bias.
// 128x128 tile, BK=64, 4 waves (each 64x64 = 4x4 frags of 16x16x32).
// LDS: linear dest for global_load_lds, source pre-swizzled, reads XOR-swizzled
// (slot ^= row&7) -> conflict-free ds_read_b128.
// MODE 0: out fp32 [M][N] (+bias0), N=1024
// MODE 1: N=3072 fused QKV -> scatter bf16 into [BH][L][HD] per segment
// ---------------------------------------------------------------------------
template <int MODE>
__global__ __launch_bounds__(256) void gemm_mfma_k(
    const __bf16* __restrict__ A, const __bf16* __restrict__ Bt,
    const float* __restrict__ bias0, const float* __restrict__ bias1,
    const float* __restrict__ bias2,
    float* __restrict__ out_f32,
    __hip_bfloat16* __restrict__ oq, __hip_bfloat16* __restrict__ ok,
    __hip_bfloat16* __restrict__ ov) {
    constexpr int K = DD;
    __shared__ __bf16 As[128 * 64];
    __shared__ __bf16 Bs[128 * 64];

    const int tid  = threadIdx.x;
    const int w    = tid >> 6;
    const int lane = tid & 63;
    const int lr   = lane & 15;
    const int lg   = lane >> 4;
    const int wr   = w >> 1, wc = w & 1;
    const int bm = blockIdx.y * 128, bn = blockIdx.x * 128;

    // staging: wave w loads rows [w*32, w*32+32) of each tile, 4 chunks of 8 rows
    const int srow = lane >> 3;                    // 0..7 row within chunk
    const int scol = ((lane & 7) ^ srow) * 8;      // pre-swizzled k-offset (elems)
    const __bf16* gA = A  + (size_t)(bm + w * 32 + srow) * K + scol;
    const __bf16* gB = Bt + (size_t)(bn + w * 32 + srow) * K + scol;
    char* ldsA = (char*)As + w * 32 * 128;
    char* ldsB = (char*)Bs + w * 32 * 128;

    f32x4 acc[4][4] = {};

    const int l7 = lr & 7;
    for (int k0 = 0; k0 < K; k0 += 64) {
#pragma unroll
        for (int c = 0; c < 4; ++c) {
            gload16(gA + (size_t)(c * 8) * K + k0, ldsA + c * 1024);
            gload16(gB + (size_t)(c * 8) * K + k0, ldsB + c * 1024);
        }
        __syncthreads();
#pragma unroll
        for (int kk = 0; kk < 2; ++kk) {
            bf16x8 a[4], b[4];
#pragma unroll
            for (int m = 0; m < 4; ++m)
                a[m] = *reinterpret_cast<const bf16x8*>(
                    As + (wr * 64 + m * 16 + lr) * 64 + (((kk * 4 + lg) ^ l7) << 3));
#pragma unroll
            for (int n = 0; n < 4; ++n)
                b[n] = *reinterpret_cast<const bf16x8*>(
                    Bs + (wc * 64 + n * 16 + lr) * 64 + (((kk * 4 + lg) ^ l7) << 3));
#pragma unroll
            for (int m = 0; m < 4; ++m)
#pragma unroll
                for (int n = 0; n < 4; ++n)
                    acc[m][n] = __builtin_amdgcn_mfma_f32_16x16x32_bf16(a[m], b[n], acc[m][n], 0, 0, 0);
        }
        __syncthreads();
    }

    if (MODE == 1) {
        const int seg = bn >> 10;
        const float* biasp = (seg == 0) ? bias0 : (seg == 1 ? bias1 : bias2);
        __hip_bfloat16* segp = (seg == 0) ? oq : (seg == 1 ? ok : ov);
#pragma unroll
        for (int n = 0; n < 4; ++n) {
            const int gn = bn + wc * 64 + n * 16 + lr;
            const int nn = gn & 1023;
            const float bv = biasp[nn];
            const int h = nn >> 6, hd = nn & 63;
#pragma unroll
            for (int m = 0; m < 4; ++m)
#pragma unroll
                for (int i = 0; i < 4; ++i) {
                    const int row = bm + wr * 64 + m * 16 + lg * 4 + i;
                    const int b = row >> 11, l = row & (LLEN - 1);
                    segp[(((size_t)(b * NHH + h)) * LLEN + l) * HDD + hd] =
                        __float2bfloat16(acc[m][n][i] + bv);
                }
        }
    } else {
#pragma unroll
        for (int n = 0; n < 4; ++n) {
            const int gn = bn + wc * 64 + n * 16 + lr;
            const float bv = bias0[gn];
#pragma unroll
            for (int m = 0; m < 4; ++m)
#pragma unroll
                for (int i = 0; i < 4; ++i) {
                    const int row = bm + wr * 64 + m * 16 + lg * 4 + i;
                    out_f32[(size_t)row * DD + gn] = acc[m][n][i] + bv;
                }
        }
    }
}

// ---------------------------------------------------------------------------
// RoPE in-place on bf16 [BH][L][HD]; pairs (d, d+32)
// ---------------------------------------------------------------------------
__global__ __launch_bounds__(256) void rope16_k(__hip_bfloat16* __restrict__ T) {
    int idx = blockIdx.x * blockDim.x + threadIdx.x;  // BH*L*32 threads
    int d = idx & 31;
    int l = (idx >> 5) & (LLEN - 1);
    int bh = idx >> 16;
    float ang = (float)l * __expf(-(float)d * 0.28782313662425572f);  // ln(1e4)/32
    float s, c;
    __sincosf(ang, &s, &c);
    __hip_bfloat16* base = T + ((size_t)bh * LLEN + l) * HDD;
    float x1 = __bfloat162float(base[d]);
    float x2 = __bfloat162float(base[d + 32]);
    base[d]      = __float2bfloat16(x1 * c - x2 * s);
    base[d + 32] = __float2bfloat16(x2 * c + x1 * s);
}

// ---------------------------------------------------------------------------
// V transpose bf16: [BH][L][HD] -> [BH][HD][L]
// ---------------------------------------------------------------------------
__global__ __launch_bounds__(256) void vt16_k(const ushort* __restrict__ in,
                                              ushort* __restrict__ out) {
    __shared__ ushort T[64][72];
    const int bh = blockIdx.y;
    const int l0 = blockIdx.x * 64;
    const int tid = threadIdx.x;
    for (int i = tid; i < 64 * 16; i += 256) {
        int r = i >> 4, c4 = (i & 15) * 4;
        ushort4 v = *reinterpret_cast<const ushort4*>(&in[((size_t)bh * LLEN + l0 + r) * HDD + c4]);
        T[r][c4 + 0] = v.x; T[r][c4 + 1] = v.y; T[r][c4 + 2] = v.z; T[r][c4 + 3] = v.w;
    }
    __syncthreads();
    int d  = tid >> 2;
    int lc = (tid & 3) * 16;
    ushort* ob = out + ((size_t)bh * HDD + d) * LLEN + l0 + lc;
#pragma unroll
    for (int j = 0; j < 16; ++j) ob[j] = T[lc + j][d];
}

// ---------------------------------------------------------------------------
// MFMA flash attention (causal), unchanged structure; epilogue now writes bf16.
// ---------------------------------------------------------------------------
__global__ __launch_bounds__(256) void attn_mfma_k(const __bf16* __restrict__ Q,
                                                   const __bf16* __restrict__ K,
                                                   const __bf16* __restrict__ Vt,
                                                   __hip_bfloat16* __restrict__ ctx) {
    __shared__ float P_lds[4][16][32];

    const int tid  = threadIdx.x;
    const int w    = tid >> 6;
    const int lane = tid & 63;
    const int lr   = lane & 15;
    const int lg   = lane >> 4;
    const int bh   = blockIdx.y;
    const int qbase = blockIdx.x * 64 + w * 16;

    const __bf16* Qh = Q  + (size_t)bh * LLEN * HDD;
    const __bf16* Kh = K  + (size_t)bh * LLEN * HDD;
    const __bf16* Vh = Vt + (size_t)bh * HDD * LLEN;

    bf16x8 qa0 = *reinterpret_cast<const bf16x8*>(Qh + (size_t)(qbase + lr) * HDD + lg * 8);
    bf16x8 qa1 = *reinterpret_cast<const bf16x8*>(Qh + (size_t)(qbase + lr) * HDD + 32 + lg * 8);

    f32x4 o0 = {0.f, 0.f, 0.f, 0.f}, o1 = o0, o2 = o0, o3 = o0;
    float mrow[4] = {-FLT_MAX, -FLT_MAX, -FLT_MAX, -FLT_MAX};
    float lrow[4] = {0.f, 0.f, 0.f, 0.f};

    const int nk = (qbase + 47) >> 5;
    for (int t = 0; t < nk; ++t) {
        const int k0 = t * 32;

        const __bf16* Kb = Kh + (size_t)(k0 + lr) * HDD + lg * 8;
        bf16x8 kb00 = *reinterpret_cast<const bf16x8*>(Kb);
        bf16x8 kb01 = *reinterpret_cast<const bf16x8*>(Kb + 32);
        bf16x8 kb10 = *reinterpret_cast<const bf16x8*>(Kb + 16 * HDD);
        bf16x8 kb11 = *reinterpret_cast<const bf16x8*>(Kb + 16 * HDD + 32);

        f32x4 s0 = {0.f, 0.f, 0.f, 0.f}, s1 = s0;
        s0 = __builtin_amdgcn_mfma_f32_16x16x32_bf16(qa0, kb00, s0, 0, 0, 0);
        s0 = __builtin_amdgcn_mfma_f32_16x16x32_bf16(qa1, kb01, s0, 0, 0, 0);
        s1 = __builtin_amdgcn_mfma_f32_16x16x32_bf16(qa0, kb10, s1, 0, 0, 0);
        s1 = __builtin_amdgcn_mfma_f32_16x16x32_bf16(qa1, kb11, s1, 0, 0, 0);

        const __bf16* Vb = Vh + (size_t)lr * LLEN + k0 + lg * 8;
        bf16x8 vb0 = *reinterpret_cast<const bf16x8*>(Vb);
        bf16x8 vb1 = *reinterpret_cast<const bf16x8*>(Vb + 16 * LLEN);
        bf16x8 vb2 = *reinterpret_cast<const bf16x8*>(Vb + 32 * LLEN);
        bf16x8 vb3 = *reinterpret_cast<const bf16x8*>(Vb + 48 * LLEN);

        float p0[4], p1[4];
#pragma unroll
        for (int i = 0; i < 4; ++i) {
            int row = qbase + lg * 4 + i;
            float a = s0[i] * 0.125f;
            float b = s1[i] * 0.125f;
            if (k0 + lr > row)      a = -FLT_MAX;
            if (k0 + 16 + lr > row) b = -FLT_MAX;
            float rm = fmaxf(a, b);
            rm = fmaxf(rm, __shfl_xor(rm, 1));
            rm = fmaxf(rm, __shfl_xor(rm, 2));
            rm = fmaxf(rm, __shfl_xor(rm, 4));
            rm = fmaxf(rm, __shfl_xor(rm, 8));
            float mn   = fmaxf(mrow[i], rm);
            float corr = __expf(mrow[i] - mn);
            float pa = __expf(a - mn);
            float pb = __expf(b - mn);
            float rs = pa + pb;
            rs += __shfl_xor(rs, 1);
            rs += __shfl_xor(rs, 2);
            rs += __shfl_xor(rs, 4);
            rs += __shfl_xor(rs, 8);
            lrow[i] = lrow[i] * corr + rs;
            mrow[i] = mn;
            o0[i] *= corr; o1[i] *= corr; o2[i] *= corr; o3[i] *= corr;
            p0[i] = pa; p1[i] = pb;
        }

#pragma unroll
        for (int i = 0; i < 4; ++i) {
            int row = lg * 4 + i;
            int h7  = row & 7;
            P_lds[w][row][((((lr) >> 2) ^ h7) << 2) | (lr & 3)]      = p0[i];
            P_lds[w][row][((((16 + lr) >> 2) ^ h7) << 2) | (lr & 3)] = p1[i];
        }

        const f32x4* pr0 = reinterpret_cast<const f32x4*>(&P_lds[w][lr][((2 * lg) ^ (lr & 7)) << 2]);
        const f32x4* pr1 = reinterpret_cast<const f32x4*>(&P_lds[w][lr][((2 * lg + 1) ^ (lr & 7)) << 2]);
        f32x4 f0 = *pr0, f1 = *pr1;
        bf16x8 pfrag;
        pfrag[0] = (__bf16)f0[0]; pfrag[1] = (__bf16)f0[1];
        pfrag[2] = (__bf16)f0[2]; pfrag[3] = (__bf16)f0[3];
        pfrag[4] = (__bf16)f1[0]; pfrag[5] = (__bf16)f1[1];
        pfrag[6] = (__bf16)f1[2]; pfrag[7] = (__bf16)f1[3];

        o0 = __builtin_amdgcn_mfma_f32_16x16x32_bf16(pfrag, vb0, o0, 0, 0, 0);
        o1 = __builtin_amdgcn_mfma_f32_16x16x32_bf16(pfrag, vb1, o1, 0, 0, 0);
        o2 = __builtin_amdgcn_mfma_f32_16x16x32_bf16(pfrag, vb2, o2, 0, 0, 0);
        o3 = __builtin_amdgcn_mfma_f32_16x16x32_bf16(pfrag, vb3, o3, 0, 0, 0);
    }

    const int b = bh >> 4, h = bh & 15;
#pragma unroll
    for (int i = 0; i < 4; ++i) {
        float inv = 1.0f / lrow[i];
        __hip_bfloat16* dst = ctx + ((size_t)(b * LLEN + qbase + lg * 4 + i)) * DD + h * HDD + lr;
        dst[0]  = __float2bfloat16(o0[i] * inv);
        dst[16] = __float2bfloat16(o1[i] * inv);
        dst[32] = __float2bfloat16(o2[i] * inv);
        dst[48] = __float2bfloat16(o3[i] * inv);
    }
}

// ---------------------------------------------------------------------------
extern "C" void kernel_launch(void* const* d_in, const int* in_sizes, int n_in,
                              void* d_out, int out_size, void* d_ws, size_t ws_size,
                              hipStream_t stream) {
    const float* x    = (const float*)d_in[0];
    const float* wq_w = (const float*)d_in[1];
    const float* wq_b = (const float*)d_in[2];
    const float* wk_w = (const float*)d_in[3];
    const float* wk_b = (const float*)d_in[4];
    const float* wv_w = (const float*)d_in[5];
    const float* wv_b = (const float*)d_in[6];
    const float* wo_w = (const float*)d_in[7];
    const float* wo_b = (const float*)d_in[8];
    float* out = (float*)d_out;

    const size_t MB = 1024 * 1024;
    char* p = (char*)d_ws;
    __bf16* x16   = (__bf16*)p;            p += 8 * MB;   // [4096][1024]
    __bf16* wqkvt = (__bf16*)p;            p += 6 * MB;   // [3072][1024]
    __bf16* wot   = (__bf16*)p;            p += 2 * MB;   // [1024][1024]
    __hip_bfloat16* q16  = (__hip_bfloat16*)p; p += 8 * MB;  // [BH][L][HD]
    __hip_bfloat16* k16  = (__hip_bfloat16*)p; p += 8 * MB;
    __hip_bfloat16* v16  = (__hip_bfloat16*)p; p += 8 * MB;
    __hip_bfloat16* v16t = (__hip_bfloat16*)p; p += 8 * MB;  // [BH][HD][L]
    __hip_bfloat16* ctx16 = (__hip_bfloat16*)p;               // [B][L][D]

    // converts
    hipLaunchKernelGGL(cvt_x_k, dim3(4096), dim3(256), 0, stream, x, (ushort*)x16);
    dim3 wtg(16, 16);
    hipLaunchKernelGGL(wt_cvt_k, wtg, dim3(256), 0, stream, wq_w, (ushort*)(wqkvt));
    hipLaunchKernelGGL(wt_cvt_k, wtg, dim3(256), 0, stream, wk_w, (ushort*)(wqkvt + (size_t)1024 * DD));
    hipLaunchKernelGGL(wt_cvt_k, wtg, dim3(256), 0, stream, wv_w, (ushort*)(wqkvt + (size_t)2048 * DD));
    hipLaunchKernelGGL(wt_cvt_k, wtg, dim3(256), 0, stream, wo_w, (ushort*)wot);

    // fused QKV projection (bf16 MFMA)
    hipLaunchKernelGGL((gemm_mfma_k<1>), dim3(24, 32), dim3(256), 0, stream,
                       x16, wqkvt, wq_b, wk_b, wv_b, (float*)nullptr, q16, k16, v16);

    // RoPE in-place on q,k
    int rope_threads = BB * NHH * LLEN * 32;
    hipLaunchKernelGGL(rope16_k, dim3(rope_threads / 256), dim3(256), 0, stream, q16);
    hipLaunchKernelGGL(rope16_k, dim3(rope_threads / 256), dim3(256), 0, stream, k16);

    // V -> [BH][HD][L]
    hipLaunchKernelGGL(vt16_k, dim3(LLEN / 64, BB * NHH), dim3(256), 0, stream,
                       (const ushort*)v16, (ushort*)v16t);

    // attention
    hipLaunchKernelGGL(attn_mfma_k, dim3(LLEN / 64, BB * NHH), dim3(256), 0, stream,
                       (const __bf16*)q16, (const __bf16*)k16, (const __bf16*)v16t, ctx16);

    // output projection (bf16 MFMA, fp32 out)
    hipLaunchKernelGGL((gemm_mfma_k<0>), dim3(8, 32), dim3(256), 0, stream,
                       (const __bf16*)ctx16, wot, wo_b, (const float*)nullptr, (const float*)nullptr,
                       out, (__hip_bfloat16*)nullptr, (__hip_bfloat16*)nullptr, (__hip_bfloat16*)nullptr);
}

// Round 4
// 176.432 us; speedup vs baseline: 7.7653x; 1.8195x over previous
//
#include <hip/hip_runtime.h>
#include <hip/hip_bf16.h>
#include <float.h>
#include <math.h>

// Problem constants: B=2, L=2048, D=1024, NH=16, HD=64
#define BB  2
#define LLEN 2048
#define DD  1024
#define NHH 16
#define HDD 64
#define MROWS (BB * LLEN)   // 4096

typedef __bf16 bf16x8  __attribute__((ext_vector_type(8)));
typedef float  f32x4   __attribute__((ext_vector_type(4)));
typedef float  f32x16  __attribute__((ext_vector_type(16)));

static __device__ __forceinline__ ushort f2bf(float f) {
    __hip_bfloat16 h = __float2bfloat16(f);
    return *reinterpret_cast<ushort*>(&h);
}

__device__ __forceinline__ void gload16(const void* g, void* l) {
    __builtin_amdgcn_global_load_lds(
        (const __attribute__((address_space(1))) void*)g,
        (__attribute__((address_space(3))) void*)l, 16, 0, 0);
}

// ---------------------------------------------------------------------------
// x fp32 -> bf16, 4 elems/thread
// ---------------------------------------------------------------------------
__global__ __launch_bounds__(256) void cvt_x_k(const float* __restrict__ in,
                                               ushort* __restrict__ out) {
    int idx = blockIdx.x * 256 + threadIdx.x;
    float4 v = reinterpret_cast<const float4*>(in)[idx];
    ushort4 o;
    o.x = f2bf(v.x); o.y = f2bf(v.y); o.z = f2bf(v.z); o.w = f2bf(v.w);
    reinterpret_cast<ushort4*>(out)[idx] = o;
}

// ---------------------------------------------------------------------------
// Weight transpose+convert: fp32 [1024][1024] -> bf16 [N][K]
// ---------------------------------------------------------------------------
__global__ __launch_bounds__(256) void wt_cvt_k(const float* __restrict__ in,
                                                ushort* __restrict__ out) {
    __shared__ float T[64][65];
    const int r0 = blockIdx.y * 64, c0 = blockIdx.x * 64;
    const int tid = threadIdx.x;
    for (int i = tid; i < 64 * 16; i += 256) {
        int r = i >> 4, c4 = (i & 15) * 4;
        float4 v = *reinterpret_cast<const float4*>(&in[(size_t)(r0 + r) * DD + c0 + c4]);
        T[r][c4 + 0] = v.x; T[r][c4 + 1] = v.y; T[r][c4 + 2] = v.z; T[r][c4 + 3] = v.w;
    }
    __syncthreads();
    for (int i = tid; i < 64 * 16; i += 256) {
        int rr = i >> 4, cc4 = (i & 15) * 4;
        ushort4 o;
        o.x = f2bf(T[cc4 + 0][rr]);
        o.y = f2bf(T[cc4 + 1][rr]);
        o.z = f2bf(T[cc4 + 2][rr]);
        o.w = f2bf(T[cc4 + 3][rr]);
        *reinterpret_cast<ushort4*>(&out[(size_t)(c0 + rr) * DD + r0 + cc4]) = o;
    }
}

// ---------------------------------------------------------------------------
// bf16 MFMA GEMM: C = A[M,K] @ Bt[N,K]^T + bias. 128x128 tile, BK=64.
// MODE 0: out fp32 [M][N]; MODE 1: N=3072 fused QKV scatter (bf16 per-head)
// ---------------------------------------------------------------------------
template <int MODE>
__global__ __launch_bounds__(256) void gemm_mfma_k(
    const __bf16* __restrict__ A, const __bf16* __restrict__ Bt,
    const float* __restrict__ bias0, const float* __restrict__ bias1,
    const float* __restrict__ bias2,
    float* __restrict__ out_f32,
    __hip_bfloat16* __restrict__ oq, __hip_bfloat16* __restrict__ ok,
    __hip_bfloat16* __restrict__ ov) {
    constexpr int K = DD;
    __shared__ __bf16 As[128 * 64];
    __shared__ __bf16 Bs[128 * 64];

    const int tid  = threadIdx.x;
    const int w    = tid >> 6;
    const int lane = tid & 63;
    const int lr   = lane & 15;
    const int lg   = lane >> 4;
    const int wr   = w >> 1, wc = w & 1;
    const int bm = blockIdx.y * 128, bn = blockIdx.x * 128;

    const int srow = lane >> 3;
    const int scol = ((lane & 7) ^ srow) * 8;
    const __bf16* gA = A  + (size_t)(bm + w * 32 + srow) * K + scol;
    const __bf16* gB = Bt + (size_t)(bn + w * 32 + srow) * K + scol;
    char* ldsA = (char*)As + w * 32 * 128;
    char* ldsB = (char*)Bs + w * 32 * 128;

    f32x4 acc[4][4] = {};

    const int l7 = lr & 7;
    for (int k0 = 0; k0 < K; k0 += 64) {
#pragma unroll
        for (int c = 0; c < 4; ++c) {
            gload16(gA + (size_t)(c * 8) * K + k0, ldsA + c * 1024);
            gload16(gB + (size_t)(c * 8) * K + k0, ldsB + c * 1024);
        }
        __syncthreads();
#pragma unroll
        for (int kk = 0; kk < 2; ++kk) {
            bf16x8 a[4], b[4];
#pragma unroll
            for (int m = 0; m < 4; ++m)
                a[m] = *reinterpret_cast<const bf16x8*>(
                    As + (wr * 64 + m * 16 + lr) * 64 + (((kk * 4 + lg) ^ l7) << 3));
#pragma unroll
            for (int n = 0; n < 4; ++n)
                b[n] = *reinterpret_cast<const bf16x8*>(
                    Bs + (wc * 64 + n * 16 + lr) * 64 + (((kk * 4 + lg) ^ l7) << 3));
#pragma unroll
            for (int m = 0; m < 4; ++m)
#pragma unroll
                for (int n = 0; n < 4; ++n)
                    acc[m][n] = __builtin_amdgcn_mfma_f32_16x16x32_bf16(a[m], b[n], acc[m][n], 0, 0, 0);
        }
        __syncthreads();
    }

    if (MODE == 1) {
        const int seg = bn >> 10;
        const float* biasp = (seg == 0) ? bias0 : (seg == 1 ? bias1 : bias2);
        __hip_bfloat16* segp = (seg == 0) ? oq : (seg == 1 ? ok : ov);
#pragma unroll
        for (int n = 0; n < 4; ++n) {
            const int gn = bn + wc * 64 + n * 16 + lr;
            const int nn = gn & 1023;
            const float bv = biasp[nn];
            const int h = nn >> 6, hd = nn & 63;
#pragma unroll
            for (int m = 0; m < 4; ++m)
#pragma unroll
                for (int i = 0; i < 4; ++i) {
                    const int row = bm + wr * 64 + m * 16 + lg * 4 + i;
                    const int b = row >> 11, l = row & (LLEN - 1);
                    segp[(((size_t)(b * NHH + h)) * LLEN + l) * HDD + hd] =
                        __float2bfloat16(acc[m][n][i] + bv);
                }
        }
    } else {
#pragma unroll
        for (int n = 0; n < 4; ++n) {
            const int gn = bn + wc * 64 + n * 16 + lr;
            const float bv = bias0[gn];
#pragma unroll
            for (int m = 0; m < 4; ++m)
#pragma unroll
                for (int i = 0; i < 4; ++i) {
                    const int row = bm + wr * 64 + m * 16 + lg * 4 + i;
                    out_f32[(size_t)row * DD + gn] = acc[m][n][i] + bv;
                }
        }
    }
}

// ---------------------------------------------------------------------------
// RoPE in-place on bf16 [BH][L][HD]; pairs (d, d+32)
// ---------------------------------------------------------------------------
__global__ __launch_bounds__(256) void rope16_k(__hip_bfloat16* __restrict__ T) {
    int idx = blockIdx.x * blockDim.x + threadIdx.x;
    int d = idx & 31;
    int l = (idx >> 5) & (LLEN - 1);
    int bh = idx >> 16;
    float ang = (float)l * __expf(-(float)d * 0.28782313662425572f);
    float s, c;
    __sincosf(ang, &s, &c);
    __hip_bfloat16* base = T + ((size_t)bh * LLEN + l) * HDD;
    float x1 = __bfloat162float(base[d]);
    float x2 = __bfloat162float(base[d + 32]);
    base[d]      = __float2bfloat16(x1 * c - x2 * s);
    base[d + 32] = __float2bfloat16(x2 * c + x1 * s);
}

// ---------------------------------------------------------------------------
// V transpose bf16: [BH][L][HD] -> [BH][HD][L]
// ---------------------------------------------------------------------------
__global__ __launch_bounds__(256) void vt16_k(const ushort* __restrict__ in,
                                              ushort* __restrict__ out) {
    __shared__ ushort T[64][72];
    const int bh = blockIdx.y;
    const int l0 = blockIdx.x * 64;
    const int tid = threadIdx.x;
    for (int i = tid; i < 64 * 16; i += 256) {
        int r = i >> 4, c4 = (i & 15) * 4;
        ushort4 v = *reinterpret_cast<const ushort4*>(&in[((size_t)bh * LLEN + l0 + r) * HDD + c4]);
        T[r][c4 + 0] = v.x; T[r][c4 + 1] = v.y; T[r][c4 + 2] = v.z; T[r][c4 + 3] = v.w;
    }
    __syncthreads();
    int d  = tid >> 2;
    int lc = (tid & 3) * 16;
    ushort* ob = out + ((size_t)bh * HDD + d) * LLEN + l0 + lc;
#pragma unroll
    for (int j = 0; j < 16; ++j) ob[j] = T[lc + j][d];
}

// ---------------------------------------------------------------------------
// Swapped-operand 32x32 MFMA flash attention (causal).
// Grid (16, BH), 256 thr = 4 waves. Wave w owns q-tile (w*16 + bx), 32 q-rows.
// QK^T: S'[kk][q] = mfma(K, Q)  -> lane col = q -> softmax lane-local.
// PV:   O^T[d][q] = mfma(V^T, P) -> lane col = q -> scalar rescale.
// P bf16 B-frags built in-register: pack + shfl_xor(32) half-lane exchange.
// No LDS, no barriers.
// mfma_f32_32x32x16_bf16: A m=lane&31, k=(lane>>5)*8+j; B n=lane&31, same k;
// C/D col=lane&31, row=(reg&3)+8*(reg>>2)+4*(lane>>5).
// ---------------------------------------------------------------------------
__global__ __launch_bounds__(256) void attn_mfma2_k(const __bf16* __restrict__ Q,
                                                    const __bf16* __restrict__ K,
                                                    const __bf16* __restrict__ Vt,
                                                    __hip_bfloat16* __restrict__ ctx) {
    const int tid  = threadIdx.x;
    const int w    = tid >> 6;
    const int lane = tid & 63;
    const int q32  = lane & 31;
    const int hi   = lane >> 5;
    const int bh   = blockIdx.y;
    const int qtile = w * 16 + blockIdx.x;  // 0..63 (interleaved for balance)
    const int qb   = qtile * 32;
    const int qg   = qb + q32;

    const __bf16* Qh = Q  + (size_t)bh * LLEN * HDD;
    const __bf16* Kh = K  + (size_t)bh * LLEN * HDD;
    const __bf16* Vh = Vt + (size_t)bh * HDD * LLEN;

    // Q B-fragments (n=q), 4 d-steps of 16
    bf16x8 qf[4];
#pragma unroll
    for (int d = 0; d < 4; ++d)
        qf[d] = *reinterpret_cast<const bf16x8*>(Qh + (size_t)qg * HDD + d * 16 + hi * 8);

    f32x16 o0 = {}, o1 = {};
    float m = -FLT_MAX, lsum = 0.f;

    for (int t = 0; t <= qtile; ++t) {
        const int k0 = t * 32;

        // K A-fragments (m=kk)
        bf16x8 kf[4];
#pragma unroll
        for (int d = 0; d < 4; ++d)
            kf[d] = *reinterpret_cast<const bf16x8*>(Kh + (size_t)(k0 + q32) * HDD + d * 16 + hi * 8);

        // V^T A-fragments (m=d), 2 d-tiles x 2 kk-halves
        const __bf16* vb = Vh + (size_t)q32 * LLEN + k0 + hi * 8;
        bf16x8 vf00 = *reinterpret_cast<const bf16x8*>(vb);
        bf16x8 vf01 = *reinterpret_cast<const bf16x8*>(vb + 16);
        bf16x8 vf10 = *reinterpret_cast<const bf16x8*>(vb + 32 * LLEN);
        bf16x8 vf11 = *reinterpret_cast<const bf16x8*>(vb + 32 * LLEN + 16);

        f32x16 s = {};
#pragma unroll
        for (int d = 0; d < 4; ++d)
            s = __builtin_amdgcn_mfma_f32_32x32x16_bf16(kf[d], qf[d], s, 0, 0, 0);

        // lane-local online softmax (lane owns q=q32; regs are 16 of 32 kk's)
        float p[16];
        float pmax = -FLT_MAX;
        if (t == qtile) {  // only last tile needs causal masking (uniform branch)
#pragma unroll
            for (int i = 0; i < 16; ++i) {
                int kkg = k0 + (i & 3) + 8 * (i >> 2) + 4 * hi;
                float v = (kkg <= qg) ? s[i] * 0.125f : -FLT_MAX;
                p[i] = v; pmax = fmaxf(pmax, v);
            }
        } else {
#pragma unroll
            for (int i = 0; i < 16; ++i) {
                float v = s[i] * 0.125f;
                p[i] = v; pmax = fmaxf(pmax, v);
            }
        }
        pmax = fmaxf(pmax, __shfl_xor(pmax, 32));
        if (!__all(pmax <= m + 2.0f)) {  // T13 defer-rescale
            float mnew = fmaxf(m, pmax);
            float corr = __expf(m - mnew);
            m = mnew;
            lsum *= corr;
#pragma unroll
            for (int i = 0; i < 16; ++i) { o0[i] *= corr; o1[i] *= corr; }
        }
        float ps = 0.f;
#pragma unroll
        for (int i = 0; i < 16; ++i) { p[i] = __expf(p[i] - m); ps += p[i]; }
        ps += __shfl_xor(ps, 32);
        lsum += ps;

        // P -> bf16 dwords + half-lane exchange -> PV B-frags (n=q, k=kk)
        unsigned u[8], x[8];
#pragma unroll
        for (int j = 0; j < 8; ++j)
            u[j] = (unsigned)f2bf(p[2 * j]) | ((unsigned)f2bf(p[2 * j + 1]) << 16);
#pragma unroll
        for (int j = 0; j < 8; ++j)
            x[j] = (unsigned)__shfl_xor((int)u[j], 32);

        union { unsigned d[4]; bf16x8 v; } B1, B2;
        if (hi == 0) {
            B1.d[0] = u[0]; B1.d[1] = u[1]; B1.d[2] = x[0]; B1.d[3] = x[1];
            B2.d[0] = u[4]; B2.d[1] = u[5]; B2.d[2] = x[4]; B2.d[3] = x[5];
        } else {
            B1.d[0] = x[2]; B1.d[1] = x[3]; B1.d[2] = u[2]; B1.d[3] = u[3];
            B2.d[0] = x[6]; B2.d[1] = x[7]; B2.d[2] = u[6]; B2.d[3] = u[7];
        }

        o0 = __builtin_amdgcn_mfma_f32_32x32x16_bf16(vf00, B1.v, o0, 0, 0, 0);
        o0 = __builtin_amdgcn_mfma_f32_32x32x16_bf16(vf01, B2.v, o0, 0, 0, 0);
        o1 = __builtin_amdgcn_mfma_f32_32x32x16_bf16(vf10, B1.v, o1, 0, 0, 0);
        o1 = __builtin_amdgcn_mfma_f32_32x32x16_bf16(vf11, B2.v, o1, 0, 0, 0);
    }

    // epilogue: O^T[d][q], lane col = q; write bf16 ctx [B][L][D]
    const float inv = 1.0f / lsum;
    const int b = bh >> 4, h = bh & 15;
    __hip_bfloat16* dst = ctx + ((size_t)(b * LLEN + qg)) * DD + h * HDD;
#pragma unroll
    for (int T = 0; T < 2; ++T) {
#pragma unroll
        for (int g = 0; g < 4; ++g) {
            int dbase = T * 32 + 8 * g + 4 * hi;
            ushort4 st;
            if (T == 0) {
                st.x = f2bf(o0[4 * g + 0] * inv);
                st.y = f2bf(o0[4 * g + 1] * inv);
                st.z = f2bf(o0[4 * g + 2] * inv);
                st.w = f2bf(o0[4 * g + 3] * inv);
            } else {
                st.x = f2bf(o1[4 * g + 0] * inv);
                st.y = f2bf(o1[4 * g + 1] * inv);
                st.z = f2bf(o1[4 * g + 2] * inv);
                st.w = f2bf(o1[4 * g + 3] * inv);
            }
            *reinterpret_cast<ushort4*>(dst + dbase) = st;
        }
    }
}

// ---------------------------------------------------------------------------
extern "C" void kernel_launch(void* const* d_in, const int* in_sizes, int n_in,
                              void* d_out, int out_size, void* d_ws, size_t ws_size,
                              hipStream_t stream) {
    const float* x    = (const float*)d_in[0];
    const float* wq_w = (const float*)d_in[1];
    const float* wq_b = (const float*)d_in[2];
    const float* wk_w = (const float*)d_in[3];
    const float* wk_b = (const float*)d_in[4];
    const float* wv_w = (const float*)d_in[5];
    const float* wv_b = (const float*)d_in[6];
    const float* wo_w = (const float*)d_in[7];
    const float* wo_b = (const float*)d_in[8];
    float* out = (float*)d_out;

    const size_t MB = 1024 * 1024;
    char* p = (char*)d_ws;
    __bf16* x16   = (__bf16*)p;            p += 8 * MB;
    __bf16* wqkvt = (__bf16*)p;            p += 6 * MB;
    __bf16* wot   = (__bf16*)p;            p += 2 * MB;
    __hip_bfloat16* q16  = (__hip_bfloat16*)p; p += 8 * MB;
    __hip_bfloat16* k16  = (__hip_bfloat16*)p; p += 8 * MB;
    __hip_bfloat16* v16  = (__hip_bfloat16*)p; p += 8 * MB;
    __hip_bfloat16* v16t = (__hip_bfloat16*)p; p += 8 * MB;
    __hip_bfloat16* ctx16 = (__hip_bfloat16*)p;

    hipLaunchKernelGGL(cvt_x_k, dim3(4096), dim3(256), 0, stream, x, (ushort*)x16);
    dim3 wtg(16, 16);
    hipLaunchKernelGGL(wt_cvt_k, wtg, dim3(256), 0, stream, wq_w, (ushort*)(wqkvt));
    hipLaunchKernelGGL(wt_cvt_k, wtg, dim3(256), 0, stream, wk_w, (ushort*)(wqkvt + (size_t)1024 * DD));
    hipLaunchKernelGGL(wt_cvt_k, wtg, dim3(256), 0, stream, wv_w, (ushort*)(wqkvt + (size_t)2048 * DD));
    hipLaunchKernelGGL(wt_cvt_k, wtg, dim3(256), 0, stream, wo_w, (ushort*)wot);

    hipLaunchKernelGGL((gemm_mfma_k<1>), dim3(24, 32), dim3(256), 0, stream,
                       x16, wqkvt, wq_b, wk_b, wv_b, (float*)nullptr, q16, k16, v16);

    int rope_threads = BB * NHH * LLEN * 32;
    hipLaunchKernelGGL(rope16_k, dim3(rope_threads / 256), dim3(256), 0, stream, q16);
    hipLaunchKernelGGL(rope16_k, dim3(rope_threads / 256), dim3(256), 0, stream, k16);

    hipLaunchKernelGGL(vt16_k, dim3(LLEN / 64, BB * NHH), dim3(256), 0, stream,
                       (const ushort*)v16, (ushort*)v16t);

    hipLaunchKernelGGL(attn_mfma2_k, dim3(16, BB * NHH), dim3(256), 0, stream,
                       (const __bf16*)q16, (const __bf16*)k16, (const __bf16*)v16t, ctx16);

    hipLaunchKernelGGL((gemm_mfma_k<0>), dim3(8, 32), dim3(256), 0, stream,
                       (const __bf16*)ctx16, wot, wo_b, (const float*)nullptr, (const float*)nullptr,
                       out, (__hip_bfloat16*)nullptr, (__hip_bfloat16*)nullptr, (__hip_bfloat16*)nullptr);
}